// Round 11
// baseline (174.826 us; speedup 1.0000x reference)
//
#include <hip/hip_runtime.h>
#include <hip/hip_bf16.h>

#define NROWS 131072
#define DK    1024
#define CCLS  21
#define CTF   84
#define NCOL  105          // 21 + 84
#define NCT   7            // 112 padded cols / 16
#define NBLK  8192         // blocks; block b owns rows {i*NBLK + b, i=0..15}

typedef __attribute__((ext_vector_type(4))) float f32x4;
typedef __attribute__((ext_vector_type(8))) short bf16x8;
typedef __attribute__((ext_vector_type(2))) unsigned int u32x2;

__device__ __forceinline__ unsigned short f2bf_rne(float x) {
    union { float f; unsigned u; } v; v.f = x;
    unsigned r = v.u + 0x7fffu + ((v.u >> 16) & 1u);
    return (unsigned short)(r >> 16);
}

__device__ __forceinline__ unsigned pack2(float lo, float hi) {
    union { float f; unsigned u; } a, b; a.f = lo; b.f = hi;
    return ((a.u + 0x8000u) >> 16) | ((b.u + 0x8000u) & 0xffff0000u);
}

// Pack [W_cls | W_tf | zero-pad] into bf16 MFMA B-fragment order (verified):
// element ((kt*NCT+ct)*64+lane)*8 + j = B[k][col],
// col = ct*16 + (lane&15), k = kt*32 + (lane>>4)*8 + j
__global__ void pack_B_kernel(const float* __restrict__ Wc,
                              const float* __restrict__ Wt,
                              unsigned short* __restrict__ Bp) {
    const int frag = blockIdx.x;           // 224 total
    const int kt = frag / NCT, ct = frag % NCT;
    const int lane = threadIdx.x;          // 64
    const int col = ct * 16 + (lane & 15);
    const int k0  = kt * 32 + ((lane >> 4) << 3);
    bf16x8 o;
#pragma unroll
    for (int j = 0; j < 8; ++j) {
        const int k = k0 + j;
        float v = 0.0f;
        if (col < CCLS)      v = Wc[k * CCLS + col];
        else if (col < NCOL) v = Wt[k * CTF + (col - CCLS)];
        o[j] = (short)f2bf_rne(v);
    }
    *reinterpret_cast<bf16x8*>(Bp + ((size_t)frag * 64 + lane) * 8) = o;
}

// Sweep-GEMM: device-wide contiguous read stream (probe-identical pattern).
// Block b stages 16 full rows {i*NBLK+b} (row = 4KB, read as 256 x f32x4),
// cvt -> bf16 into 32KB XOR-swizzled LDS, MFMA K-split across 4 waves,
// cross-wave LDS reduce (overlaying the tile), bias + store.
__global__ __launch_bounds__(256)
void roi_gemm_kernel(const float* __restrict__ F,
                     const unsigned short* __restrict__ Bp,
                     const float* __restrict__ bcls,
                     const float* __restrict__ btf,
                     float* __restrict__ out) {
    __shared__ __align__(16) unsigned char smem[16 * 2048];   // 32 KiB

    const int t    = threadIdx.x;
    const int wave = t >> 6;
    const int lane = t & 63;
    const int fr   = lane & 15;          // A row-in-tile / B col
    const int fq   = lane >> 4;          // 0..3
    const int b    = blockIdx.x;

    // bias registers for the reduce phase (col depends only on t and ct)
    const int rcol0 = (t >> 2) & 15;
    float biasr[NCT];
#pragma unroll
    for (int ct = 0; ct < NCT; ++ct) {
        const int col = ct * 16 + rcol0;
        biasr[ct] = (col < CCLS) ? bcls[col]
                  : (col < NCOL) ? btf[col - CCLS] : 0.0f;
    }

    // ---- stage 16 full rows in two register passes of 8 (VGPR control).
    // Row j: 256 threads x f32x4 = 4KB contiguous (each wave = 1KB instr).
    // LDS tile [16][2048B bf16]; 16B-chunk index swizzled ch ^= (j&7):
    // thread t holds k-bytes [8t,8t+8) = chunk t>>1, half t&1.
#pragma unroll
    for (int half = 0; half < 2; ++half) {
        f32x4 v[8];
#pragma unroll
        for (int j = 0; j < 8; ++j)
            v[j] = *reinterpret_cast<const f32x4*>(
                F + ((size_t)(half * 8 + j) * NBLK + b) * DK + t * 4);
#pragma unroll
        for (int j = 0; j < 8; ++j) {
            const int R = half * 8 + j;
            u32x2 d;
            d[0] = pack2(v[j][0], v[j][1]);
            d[1] = pack2(v[j][2], v[j][3]);
            *reinterpret_cast<u32x2*>(
                smem + R * 2048 + (((t >> 1) ^ (R & 7)) << 4) + ((t & 1) << 3)) = d;
        }
    }
    __syncthreads();

    // ---- MFMA: K split across waves — wave w handles k-tiles w*8..w*8+7
    f32x4 acc[NCT];
#pragma unroll
    for (int ct = 0; ct < NCT; ++ct) acc[ct] = (f32x4){0.f, 0.f, 0.f, 0.f};

    const unsigned short* bb = Bp + (size_t)lane * 8;
    const int w8 = wave * 8;

#pragma unroll
    for (int jj = 0; jj < 8; ++jj) {
        const int kt = w8 + jj;
        bf16x8 bfr[NCT];
#pragma unroll
        for (int ct = 0; ct < NCT; ++ct)
            bfr[ct] = *reinterpret_cast<const bf16x8*>(
                bb + ((size_t)(kt * NCT + ct) * 512));
        const bf16x8 a = *reinterpret_cast<const bf16x8*>(
            smem + fr * 2048 + ((((kt << 2) | fq) ^ (fr & 7)) << 4));
#pragma unroll
        for (int ct = 0; ct < NCT; ++ct)
            acc[ct] = __builtin_amdgcn_mfma_f32_16x16x32_bf16(
                a, bfr[ct], acc[ct], 0, 0, 0);
    }

    // ---- cross-wave K reduction through LDS (overlay the consumed tile)
    __syncthreads();
#pragma unroll
    for (int ct = 0; ct < NCT; ++ct)
        *reinterpret_cast<f32x4*>(
            smem + (((wave * NCT + ct) << 10) + (lane << 4))) = acc[ct];
    __syncthreads();

    // ---- reduce 4 partials + bias + store.
    // Slot f32 index t: col = ct*16 + ((t>>2)&15), Mrow = ((t>>6)<<2)+(t&3).
    const float* sf = reinterpret_cast<const float*>(smem);
    float* out_tf = out + (size_t)NROWS * CCLS;
    const long grow = (long)(((t >> 6) << 2) + (t & 3)) * NBLK + b;
#pragma unroll
    for (int ct = 0; ct < NCT; ++ct) {
        const int col = ct * 16 + rcol0;
        if (col >= NCOL) continue;
        const float v = sf[(0 * NCT + ct) * 256 + t] +
                        sf[(1 * NCT + ct) * 256 + t] +
                        sf[(2 * NCT + ct) * 256 + t] +
                        sf[(3 * NCT + ct) * 256 + t] + biasr[ct];
        if (col < CCLS) out[grow * CCLS + col] = v;
        else            out_tf[grow * CTF + (col - CCLS)] = v;
    }
}

extern "C" void kernel_launch(void* const* d_in, const int* in_sizes, int n_in,
                              void* d_out, int out_size, void* d_ws, size_t ws_size,
                              hipStream_t stream) {
    const float* F  = (const float*)d_in[0];
    const float* Wc = (const float*)d_in[1];
    const float* bc = (const float*)d_in[2];
    const float* Wt = (const float*)d_in[3];
    const float* bt = (const float*)d_in[4];
    unsigned short* Bp = (unsigned short*)d_ws;   // 229,376 B

    pack_B_kernel<<<NCT * (DK / 32), 64, 0, stream>>>(Wc, Wt, Bp);
    roi_gemm_kernel<<<NBLK, 256, 0, stream>>>(F, Bp, bc, bt, (float*)d_out);
}

// Round 12
// 154.458 us; speedup vs baseline: 1.1319x; 1.1319x over previous
//
#include <hip/hip_runtime.h>
#include <hip/hip_bf16.h>

#define NROWS 131072
#define DK    1024
#define CCLS  21
#define CTF   84
#define NCOL  105          // 21 + 84
#define NCT   7            // 112 padded cols / 16
#define BM    16           // rows per block = one MFMA row-tile
#define SLABF 256          // f32 per row per slab = 1KB contiguous per visit
#define NSLAB (DK / SLABF) // 4
#define ROWB  1040         // padded LDS row-slab stride (1024 + 16) bytes

typedef __attribute__((ext_vector_type(4))) float f32x4;
typedef __attribute__((ext_vector_type(8))) short bf16x8;

typedef const __attribute__((address_space(1))) void GV;
typedef __attribute__((address_space(3))) void LV;

__device__ __forceinline__ unsigned short f2bf_rne(float x) {
    union { float f; unsigned u; } v; v.f = x;
    unsigned r = v.u + 0x7fffu + ((v.u >> 16) & 1u);
    return (unsigned short)(r >> 16);
}

__device__ __forceinline__ unsigned pack2(float lo, float hi) {
    union { float f; unsigned u; } a, b; a.f = lo; b.f = hi;
    return ((a.u + 0x8000u) >> 16) | ((b.u + 0x8000u) & 0xffff0000u);
}

__device__ __forceinline__ bf16x8 cvt8v(const f32x4 lo, const f32x4 hi) {
    union { unsigned u[4]; bf16x8 v; } r;
    r.u[0] = pack2(lo[0], lo[1]);
    r.u[1] = pack2(lo[2], lo[3]);
    r.u[2] = pack2(hi[0], hi[1]);
    r.u[3] = pack2(hi[2], hi[3]);
    return r.v;
}

// Pack [W_cls | W_tf | zero-pad] into bf16 MFMA B-fragment order (verified):
// element ((kt*NCT+ct)*64+lane)*8 + j = B[k][col],
// col = ct*16 + (lane&15), k = kt*32 + (lane>>4)*8 + j
__global__ void pack_B_kernel(const float* __restrict__ Wc,
                              const float* __restrict__ Wt,
                              unsigned short* __restrict__ Bp) {
    const int frag = blockIdx.x;           // 224 total
    const int kt = frag / NCT, ct = frag % NCT;
    const int lane = threadIdx.x;          // 64
    const int col = ct * 16 + (lane & 15);
    const int k0  = kt * 32 + ((lane >> 4) << 3);
    bf16x8 o;
#pragma unroll
    for (int j = 0; j < 8; ++j) {
        const int k = k0 + j;
        float v = 0.0f;
        if (col < CCLS)      v = Wc[k * CCLS + col];
        else if (col < NCOL) v = Wt[k * CTF + (col - CCLS)];
        o[j] = (short)f2bf_rne(v);
    }
    *reinterpret_cast<bf16x8*>(Bp + ((size_t)frag * 64 + lane) * 8) = o;
}

// Probe-pattern pipelined GEMM: block = 16 consecutive rows. Each DMA
// instruction = 1KB CONTIGUOUS of one row (probe-identical page visit);
// double-buffered, counted vmcnt(4) + raw s_barrier (no drain) keeps reads
// issued 100% of the time. LDS rows padded +16B -> bank-optimal ds_read with
// a purely linear DMA source. K split across 4 waves; LDS reduce at end.
__global__ __launch_bounds__(256, 4)
void roi_gemm_kernel(const float* __restrict__ F,
                     const unsigned short* __restrict__ Bp,
                     const float* __restrict__ bcls,
                     const float* __restrict__ btf,
                     float* __restrict__ out) {
    __shared__ __align__(16) unsigned char smem[2 * BM * ROWB];  // 33,280 B

    const int t    = threadIdx.x;
    const int wave = t >> 6;
    const int lane = t & 63;
    const int fr   = lane & 15;      // A row-in-tile / C col
    const int fq   = lane >> 4;      // 0..3
    const long rw  = (long)blockIdx.x * BM;

    // bias registers for the reduce phase
    const int rcol0 = (t >> 2) & 15;
    float biasr[NCT];
#pragma unroll
    for (int ct = 0; ct < NCT; ++ct) {
        const int col = ct * 16 + rcol0;
        biasr[ct] = (col < CCLS) ? bcls[col]
                  : (col < NCOL) ? btf[col - CCLS] : 0.0f;
    }

    const unsigned short* bb = Bp + (size_t)lane * 8;

    f32x4 acc[NCT];
#pragma unroll
    for (int ct = 0; ct < NCT; ++ct) acc[ct] = (f32x4){0.f, 0.f, 0.f, 0.f};

    // wave w stages rows w*4..w*4+3; one instruction = 1KB contiguous of
    // one row (64 lanes x 16B, linear source AND linear LDS dest).
#define STAGE(BUF, S) do {                                                    \
    _Pragma("unroll")                                                         \
    for (int q = 0; q < 4; ++q) {                                             \
        const int row = wave * 4 + q;                                         \
        __builtin_amdgcn_global_load_lds(                                     \
            (GV*)(F + ((size_t)(rw + row)) * DK + (size_t)(S) * SLABF         \
                  + lane * 4),                                                \
            (LV*)(smem + (BUF) * BM * ROWB + row * ROWB), 16, 0, 0);          \
    }                                                                         \
} while (0)

    STAGE(0, 0);   // prologue

    for (int s = 0; s < NSLAB; ++s) {
        const int buf = s & 1;

        if (s + 1 < NSLAB) {
            STAGE(buf ^ 1, s + 1);
            __builtin_amdgcn_sched_barrier(0);
            // FIFO: [DMA(s)=4][B(s-1) done][DMA(s+1)=4] -> keep newest 4
            asm volatile("s_waitcnt vmcnt(4)" ::: "memory");
        } else {
            asm volatile("s_waitcnt vmcnt(0)" ::: "memory");
        }
        __builtin_amdgcn_sched_barrier(0);
        __builtin_amdgcn_s_barrier();          // slab s fully staged
        __builtin_amdgcn_sched_barrier(0);

        // compute: wave w covers local k-tiles w*2, w*2+1 of this slab
        const unsigned char* bufb = smem + buf * BM * ROWB;
#pragma unroll
        for (int jj = 0; jj < 2; ++jj) {
            const int ktg = s * 8 + wave * 2 + jj;
            bf16x8 bfr[NCT];
#pragma unroll
            for (int ct = 0; ct < NCT; ++ct)
                bfr[ct] = *reinterpret_cast<const bf16x8*>(
                    bb + ((size_t)(ktg * NCT + ct) * 512));
            const unsigned char* ap =
                bufb + fr * ROWB + (wave * 2 + jj) * 128 + fq * 32;
            const f32x4 lo = *reinterpret_cast<const f32x4*>(ap);
            const f32x4 hi = *reinterpret_cast<const f32x4*>(ap + 16);
            const bf16x8 a = cvt8v(lo, hi);
#pragma unroll
            for (int ct = 0; ct < NCT; ++ct)
                acc[ct] = __builtin_amdgcn_mfma_f32_16x16x32_bf16(
                    a, bfr[ct], acc[ct], 0, 0, 0);
        }

        __builtin_amdgcn_sched_barrier(0);
        __builtin_amdgcn_s_barrier();          // WAR: buf free to overwrite
        __builtin_amdgcn_sched_barrier(0);
    }
#undef STAGE

    // ---- cross-wave K reduction through LDS (overlay the staging buffer)
    float* sf = reinterpret_cast<float*>(smem);
#pragma unroll
    for (int ct = 0; ct < NCT; ++ct)
        *reinterpret_cast<f32x4*>(sf + ((wave * NCT + ct) << 8) + (lane << 2)) =
            acc[ct];
    __syncthreads();

    // slot f32 index t: col = ct*16 + ((t>>2)&15), Mrow = ((t>>6)<<2)+(t&3)
    float* out_tf = out + (size_t)NROWS * CCLS;
    const long grow = rw + ((t >> 6) << 2) + (t & 3);
#pragma unroll
    for (int ct = 0; ct < NCT; ++ct) {
        const int col = ct * 16 + rcol0;
        if (col >= NCOL) continue;
        const float v = sf[(0 * NCT + ct) * 256 + t] +
                        sf[(1 * NCT + ct) * 256 + t] +
                        sf[(2 * NCT + ct) * 256 + t] +
                        sf[(3 * NCT + ct) * 256 + t] + biasr[ct];
        if (col < CCLS) out[grow * CCLS + col] = v;
        else            out_tf[grow * CTF + (col - CCLS)] = v;
    }
}

extern "C" void kernel_launch(void* const* d_in, const int* in_sizes, int n_in,
                              void* d_out, int out_size, void* d_ws, size_t ws_size,
                              hipStream_t stream) {
    const float* F  = (const float*)d_in[0];
    const float* Wc = (const float*)d_in[1];
    const float* bc = (const float*)d_in[2];
    const float* Wt = (const float*)d_in[3];
    const float* bt = (const float*)d_in[4];
    unsigned short* Bp = (unsigned short*)d_ws;   // 229,376 B

    pack_B_kernel<<<NCT * (DK / 32), 64, 0, stream>>>(Wc, Wt, Bp);
    roi_gemm_kernel<<<NROWS / BM, 256, 0, stream>>>(F, Bp, bc, bt,
                                                    (float*)d_out);
}

// Round 13
// 145.126 us; speedup vs baseline: 1.2046x; 1.0643x over previous
//
#include <hip/hip_runtime.h>
#include <hip/hip_bf16.h>

#define NROWS 131072
#define DK    1024
#define CCLS  21
#define CTF   84
#define NCOL  105          // 21 + 84
#define NCT   7            // 112 padded cols / 16
#define BM    16           // rows per block = one MFMA row-tile
#define SLABF 256          // f32 per row per slab = 1KB contiguous per load
#define NSLAB (DK / SLABF) // 4

typedef __attribute__((ext_vector_type(4))) float f32x4;
typedef __attribute__((ext_vector_type(8))) short bf16x8;
typedef __attribute__((ext_vector_type(2))) unsigned int u32x2;

__device__ __forceinline__ unsigned short f2bf_rne(float x) {
    union { float f; unsigned u; } v; v.f = x;
    unsigned r = v.u + 0x7fffu + ((v.u >> 16) & 1u);
    return (unsigned short)(r >> 16);
}

__device__ __forceinline__ unsigned pack2(float lo, float hi) {
    union { float f; unsigned u; } a, b; a.f = lo; b.f = hi;
    return ((a.u + 0x8000u) >> 16) | ((b.u + 0x8000u) & 0xffff0000u);
}

// Pack [W_cls | W_tf | zero-pad] into bf16 MFMA B-fragment order (verified):
// element ((kt*NCT+ct)*64+lane)*8 + j = B[k][col],
// col = ct*16 + (lane&15), k = kt*32 + (lane>>4)*8 + j
__global__ void pack_B_kernel(const float* __restrict__ Wc,
                              const float* __restrict__ Wt,
                              unsigned short* __restrict__ Bp) {
    const int frag = blockIdx.x;           // 224 total
    const int kt = frag / NCT, ct = frag % NCT;
    const int lane = threadIdx.x;          // 64
    const int col = ct * 16 + (lane & 15);
    const int k0  = kt * 32 + ((lane >> 4) << 3);
    bf16x8 o;
#pragma unroll
    for (int j = 0; j < 8; ++j) {
        const int k = k0 + j;
        float v = 0.0f;
        if (col < CCLS)      v = Wc[k * CCLS + col];
        else if (col < NCOL) v = Wt[k * CTF + (col - CCLS)];
        o[j] = (short)f2bf_rne(v);
    }
    *reinterpret_cast<bf16x8*>(Bp + ((size_t)frag * 64 + lane) * 8) = o;
}

// Reg-staged GEMM with FIFO-correct prefetch: per slab, issue order is
// [B x14][A(s+1) x4] so compute's B-waits retire ONLY B (vmcnt FIFO) and the
// A prefetch stays in flight through compute + write. VGPR loads (probe-
// proven 6.3 TB/s path), 1KB contiguous per instruction. XOR-swizzled LDS
// on both write and read sides (reg-staged, rule-21 clean).
__global__ __launch_bounds__(256, 4)
void roi_gemm_kernel(const float* __restrict__ F,
                     const unsigned short* __restrict__ Bp,
                     const float* __restrict__ bcls,
                     const float* __restrict__ btf,
                     float* __restrict__ out) {
    // staging: 2 bufs x 16 rows x 512B bf16 = 16 KB; reduce overlay = 28 KB
    __shared__ __align__(16) unsigned char smem[28672];

    const int t    = threadIdx.x;
    const int wave = t >> 6;
    const int lane = t & 63;
    const int fr   = lane & 15;      // A row-in-tile / B col
    const int fq   = lane >> 4;      // 0..3
    const long rw  = (long)blockIdx.x * BM;

    const unsigned short* bb = Bp + (size_t)lane * 8;
    // wave stages rows wave*4..wave*4+3; lane covers 16B at col lane*4
    const float* abase = F + (size_t)(rw + wave * 4) * DK + lane * 4;

    f32x4 acc[NCT];
#pragma unroll
    for (int ct = 0; ct < NCT; ++ct) acc[ct] = (f32x4){0.f, 0.f, 0.f, 0.f};

    // LDS addresses (bf16 tile, 512B/row, 16B-chunk XOR swizzle by row&7):
    //  write row R=wave*4+q: byte = buf*8192 + R*512
    //        + (((lane>>1) ^ (R&7))<<4) + ((lane&1)<<3)
    //  read  k-tile lt:      byte = buf*8192 + fr*512
    //        + ((((lt<<2)|fq) ^ (fr&7))<<4)
#define AWADDR(BUF, Q) (smem + (BUF) * 8192 + (wave * 4 + (Q)) * 512 +        \
    (((lane >> 1) ^ ((wave * 4 + (Q)) & 7)) << 4) + ((lane & 1) << 3))

    // ---- prologue: load + write slab 0
    {
        f32x4 v0[4];
#pragma unroll
        for (int q = 0; q < 4; ++q)
            v0[q] = *reinterpret_cast<const f32x4*>(abase + (size_t)q * DK);
#pragma unroll
        for (int q = 0; q < 4; ++q) {
            u32x2 d;
            d[0] = pack2(v0[q][0], v0[q][1]);
            d[1] = pack2(v0[q][2], v0[q][3]);
            *reinterpret_cast<u32x2*>(AWADDR(0, q)) = d;
        }
    }
    __syncthreads();

#pragma unroll
    for (int s = 0; s < NSLAB; ++s) {
        const int buf = s & 1;

        // [1] ALL B-fragment loads for slab s — FIRST in the VMEM FIFO
        bf16x8 bfr[2][NCT];
#pragma unroll
        for (int jj = 0; jj < 2; ++jj) {
            const int ktg = s * 8 + wave * 2 + jj;
#pragma unroll
            for (int ct = 0; ct < NCT; ++ct)
                bfr[jj][ct] = *reinterpret_cast<const bf16x8*>(
                    bb + ((size_t)(ktg * NCT + ct) * 512));
        }
        __builtin_amdgcn_sched_barrier(0);

        // [2] A prefetch for slab s+1 — AFTER B, so B-waits keep it in flight
        f32x4 v[4];
        if (s + 1 < NSLAB) {
#pragma unroll
            for (int q = 0; q < 4; ++q)
                v[q] = *reinterpret_cast<const f32x4*>(
                    abase + (size_t)q * DK + (s + 1) * SLABF);
        }
        __builtin_amdgcn_sched_barrier(0);

        // [3] compute slab s (B-waits are counted: vmcnt retires only B)
#pragma unroll
        for (int jj = 0; jj < 2; ++jj) {
            const int lt = wave * 2 + jj;
            const bf16x8 a = *reinterpret_cast<const bf16x8*>(
                smem + buf * 8192 + fr * 512 +
                ((((lt << 2) | fq) ^ (fr & 7)) << 4));
#pragma unroll
            for (int ct = 0; ct < NCT; ++ct)
                acc[ct] = __builtin_amdgcn_mfma_f32_16x16x32_bf16(
                    a, bfr[jj][ct], acc[ct], 0, 0, 0);
        }
        __builtin_amdgcn_sched_barrier(0);

        // [4] cvt + write slab s+1 into the other buffer (A-wait lands here)
        if (s + 1 < NSLAB) {
#pragma unroll
            for (int q = 0; q < 4; ++q) {
                u32x2 d;
                d[0] = pack2(v[q][0], v[q][1]);
                d[1] = pack2(v[q][2], v[q][3]);
                *reinterpret_cast<u32x2*>(AWADDR(buf ^ 1, q)) = d;
            }
        }
        __syncthreads();   // publish slab s+1 (outstanding VMEM is 0 here)
    }
#undef AWADDR

    // ---- cross-wave K reduction through LDS (overlay; verified in R12)
    float* sf = reinterpret_cast<float*>(smem);
#pragma unroll
    for (int ct = 0; ct < NCT; ++ct)
        *reinterpret_cast<f32x4*>(sf + ((wave * NCT + ct) << 8) + (lane << 2)) =
            acc[ct];
    __syncthreads();

    // reduce 4 partials + bias + store (verified in R12):
    // slot f32 index t: col = ct*16 + ((t>>2)&15), Mrow = ((t>>6)<<2)+(t&3)
    const int rcol0 = (t >> 2) & 15;
    float* out_tf = out + (size_t)NROWS * CCLS;
    const long grow = rw + ((t >> 6) << 2) + (t & 3);
#pragma unroll
    for (int ct = 0; ct < NCT; ++ct) {
        const int col = ct * 16 + rcol0;
        if (col >= NCOL) continue;
        const float v = sf[(0 * NCT + ct) * 256 + t] +
                        sf[(1 * NCT + ct) * 256 + t] +
                        sf[(2 * NCT + ct) * 256 + t] +
                        sf[(3 * NCT + ct) * 256 + t] +
                        ((col < CCLS) ? bcls[col] : btf[col - CCLS]);
        if (col < CCLS) out[grow * CCLS + col] = v;
        else            out_tf[grow * CTF + (col - CCLS)] = v;
    }
}

extern "C" void kernel_launch(void* const* d_in, const int* in_sizes, int n_in,
                              void* d_out, int out_size, void* d_ws, size_t ws_size,
                              hipStream_t stream) {
    const float* F  = (const float*)d_in[0];
    const float* Wc = (const float*)d_in[1];
    const float* bc = (const float*)d_in[2];
    const float* Wt = (const float*)d_in[3];
    const float* bt = (const float*)d_in[4];
    unsigned short* Bp = (unsigned short*)d_ws;   // 229,376 B

    pack_B_kernel<<<NCT * (DK / 32), 64, 0, stream>>>(Wc, Wt, Bp);
    roi_gemm_kernel<<<NROWS / BM, 256, 0, stream>>>(F, Bp, bc, bt,
                                                    (float*)d_out);
}